// Round 9
// baseline (1683.785 us; speedup 1.0000x reference)
//
#include <hip/hip_runtime.h>

#define POP   128
#define BATCH 256
#define DIN   1024
#define DOUT  1024

#define BM 256            // full batch: w panel loaded once
#define BN 256            // x panel loaded 4x
#define BK 64
#define NKT (DIN / BK)    // 16

typedef __attribute__((ext_vector_type(8))) short  short8v;
typedef __attribute__((ext_vector_type(4))) short  short4v;
typedef __attribute__((ext_vector_type(4))) float  float4v;

// fp32 -> bf16 round-to-nearest-even (inputs are finite Gaussians; no NaN path)
static __device__ __forceinline__ short f2bf(float f) {
    unsigned u = __builtin_bit_cast(unsigned, f);
    u += 0x7fffu + ((u >> 16) & 1u);
    return (short)(u >> 16);
}

// LDS-only barrier (HW-verified rounds 3/6): drains lgkm (ds + smem) but NOT
// vmcnt, so staged vector loads stay in flight across it. Also serves as the
// once-per-iter drain of the fire-and-forget scalar prefetches (issued just
// before it), guaranteeing prefetched lines are L2-resident afterwards.
static __device__ __forceinline__ void lds_barrier() {
    asm volatile("s_waitcnt lgkmcnt(0)\n\ts_barrier" ::: "memory");
}

// Force a wave-uniform 64-bit value into SGPRs (HK readfirstlane hoist).
// The prefetch base depends only on (wave, p, n_base) -> uniform in fact,
// but divergence analysis can't prove it from threadIdx; readfirstlane can.
static __device__ __forceinline__ unsigned long long uniform_u64(unsigned long long a) {
    unsigned lo = __builtin_amdgcn_readfirstlane((unsigned)a);
    unsigned hi = __builtin_amdgcn_readfirstlane((unsigned)(a >> 32));
    return ((unsigned long long)hi << 32) | (unsigned long long)lo;
}

// Fire-and-forget L2 prefetch of 256 contiguous bytes via the SCALAR miss pipe.
// Dest SGPRs are a dedicated clobbered block, never read (values are garbage;
// out-of-order SMEM returns are harmless). Purpose: pull the w-stream into L2
// through a miss queue PARALLEL to the vector TCP's (the ~3 TB/s read wall).
static __device__ __forceinline__ void sprefetch256(unsigned long long a) {
    asm volatile("s_load_dwordx16 s[48:63], %0, 0x0\n\t"
                 "s_load_dwordx16 s[48:63], %0, 0x40\n\t"
                 "s_load_dwordx16 s[48:63], %0, 0x80\n\t"
                 "s_load_dwordx16 s[48:63], %0, 0xc0"
                 :: "s"(a)
                 : "s48","s49","s50","s51","s52","s53","s54","s55",
                   "s56","s57","s58","s59","s60","s61","s62","s63");
}

__global__ __launch_bounds__(512, 2)
void pop_linear_kernel(const float* __restrict__ x,
                       const float* __restrict__ w,
                       const float* __restrict__ bias,
                       float* __restrict__ out) {
    // bf16 tiles [256 rows][64 k], row stride 128 B, single-buffered: 64 KB total.
    // In-row bytes XOR-swizzled: phys = logical ^ ((row&7)<<4), both sides (T2).
    __shared__ short As[BM * BK];   // 32 KB
    __shared__ short Bs[BN * BK];   // 32 KB

    // grid 512 = 128 pops x 4 n_tiles; bid%8 == p%8 -> x-panel sharers on one XCD
    const int bid    = blockIdx.x;
    const int k      = bid >> 3;
    const int n_tile = k & 3;
    const int p      = ((k >> 2) << 3) | (bid & 7);

    const int tid    = threadIdx.x;        // 0..511
    const int lane   = tid & 63;
    const int wave   = tid >> 6;           // 0..7 = 2(m) x 4(n)
    const int wm     = wave >> 2;          // 0..1  (row half: 128 rows)
    const int wn     = wave & 3;           // 0..3  (col quarter: 64 cols)
    const int lane15 = lane & 15;
    const int quad   = lane >> 4;          // 0..3

    const int n_base = n_tile * BN;

    // staging: thread -> row srow + 32*ps (8 passes), 256 B per row by 16 lanes
    const int srow  = tid >> 4;            // 0..31
    const int scolf = (tid & 15) * 4;      // 0..60 (floats)

    const float* Ag = x + (size_t)srow * (POP * DIN) + (size_t)p * DIN + scolf;
    const float* Bg = w + (size_t)p * ((size_t)DOUT * DIN) + (size_t)(n_base + srow) * DIN + scolf;

    // scalar-prefetch base: this wave's 32 rows of the B (w) tile (SGPR-hoisted)
    const unsigned long long wpf = uniform_u64(
        (unsigned long long)(w + (size_t)p * ((size_t)DOUT * DIN) + (size_t)(n_base + wave * 32) * DIN));

    const int swz = (scolf * 2) ^ ((srow & 7) << 4);

    float4v acc[8][4];
    #pragma unroll
    for (int i = 0; i < 8; ++i)
        #pragma unroll
        for (int j = 0; j < 4; ++j)
            acc[i][j] = (float4v){0.f, 0.f, 0.f, 0.f};

    float4v avr[8], bvr[8];

    const int frx = (lane15 & 7) << 4;
    const char* Ac = (const char*)As;
    const char* Bc = (const char*)Bs;

    // ---- prologue: issue stage 0; prefetch w tiles 0 and 1 via scalar pipe ----
    #pragma unroll
    for (int ps = 0; ps < 8; ++ps) {
        avr[ps] = *(const float4v*)(Ag + (size_t)(ps * 32) * (POP * DIN));
        bvr[ps] = *(const float4v*)(Bg + (size_t)(ps * 32) * DIN);
    }
    #pragma unroll 1
    for (int r = 0; r < 32; ++r) {
        sprefetch256(wpf + (unsigned long long)r * (DIN * 4));            // tile 0 (late, but warms)
        sprefetch256(wpf + (unsigned long long)r * (DIN * 4) + BK * 4);   // tile 1
    }

    #pragma unroll 1
    for (int kt = 0; kt < NKT; ++kt) {
        lds_barrier();   // reads of prev tile done; scalar prefetches drained -> in L2

        // convert + publish (compiler inserts exact vmcnt waits for avr/bvr)
        #pragma unroll
        for (int ps = 0; ps < 8; ++ps) {
            short4v a4, b4;
            #pragma unroll
            for (int e = 0; e < 4; ++e) {
                a4[e] = f2bf(avr[ps][e]);
                b4[e] = f2bf(bvr[ps][e]);
            }
            *(short4v*)((char*)As + (ps * 32 + srow) * 128 + swz) = a4;
            *(short4v*)((char*)Bs + (ps * 32 + srow) * 128 + swz) = b4;
        }

        lds_barrier();   // writes visible

        // issue next stage (w side should now be L2-hit thanks to prefetch)
        if (kt + 1 < NKT) {
            const size_t k0 = (size_t)(kt + 1) * BK;
            #pragma unroll
            for (int ps = 0; ps < 8; ++ps) {
                avr[ps] = *(const float4v*)(Ag + (size_t)(ps * 32) * (POP * DIN) + k0);
                bvr[ps] = *(const float4v*)(Bg + (size_t)(ps * 32) * DIN + k0);
            }
        }

        // compute: 2 k-chunks of 32; per wave 8x4 fragments, 64 MFMA per step
        #pragma unroll
        for (int kk = 0; kk < 2; ++kk) {
            const int cb = (kk * 64 + quad * 16) ^ frx;
            short8v bfr[4];
            #pragma unroll
            for (int j = 0; j < 4; ++j)
                bfr[j] = *(const short8v*)(Bc + (wn * 64 + j * 16 + lane15) * 128 + cb);
            #pragma unroll
            for (int i = 0; i < 8; ++i) {
                short8v afr = *(const short8v*)(Ac + (wm * 128 + i * 16 + lane15) * 128 + cb);
                #pragma unroll
                for (int j = 0; j < 4; ++j)
                    acc[i][j] = __builtin_amdgcn_mfma_f32_16x16x32_bf16(afr, bfr[j], acc[i][j], 0, 0, 0);
            }
        }

        // scalar-prefetch w tile kt+2 (end-of-compute placement: its lgkm drain
        // lands on the next lds_barrier, once per iter, in parallel with the
        // vector pipe -- NOT inside the ds_read->MFMA waits)
        if (kt + 2 < NKT) {
            const unsigned long long pb = wpf + (unsigned long long)(kt + 2) * (BK * 4);
            #pragma unroll 1
            for (int r = 0; r < 32; ++r)
                sprefetch256(pb + (unsigned long long)r * (DIN * 4));
        }
    }

    // epilogue: C/D layout m = quad*4 + reg, n = lane&15 (HW-verified mapping)
    const float* bp = bias + (size_t)p * DOUT;
    float bj[4];
    #pragma unroll
    for (int j = 0; j < 4; ++j)
        bj[j] = bp[n_base + wn * 64 + j * 16 + lane15];

    #pragma unroll
    for (int i = 0; i < 8; ++i) {
        #pragma unroll
        for (int r = 0; r < 4; ++r) {
            const int m = wm * 128 + i * 16 + quad * 4 + r;
            float* orow = out + (size_t)m * (POP * DOUT) + (size_t)p * DOUT;
            #pragma unroll
            for (int j = 0; j < 4; ++j) {
                const int n = n_base + wn * 64 + j * 16 + lane15;
                orow[n] = acc[i][j][r] + bj[j];
            }
        }
    }
}

extern "C" void kernel_launch(void* const* d_in, const int* in_sizes, int n_in,
                              void* d_out, int out_size, void* d_ws, size_t ws_size,
                              hipStream_t stream) {
    const float* x    = (const float*)d_in[0];
    const float* w    = (const float*)d_in[1];
    const float* bias = (const float*)d_in[2];
    float* out        = (float*)d_out;

    const int grid = POP * (DOUT / BN);  // 128 * 4 = 512
    pop_linear_kernel<<<grid, 512, 0, stream>>>(x, w, bias, out);
}

// Round 10
// 821.886 us; speedup vs baseline: 2.0487x; 2.0487x over previous
//
#include <hip/hip_runtime.h>

#define POP   128
#define BATCH 256
#define DIN   1024
#define DOUT  1024

#define BM 256            // full batch: w panel loaded once (compulsory)
#define BN 256            // x panel loaded 4x (issued), L2-shared on one XCD
#define BK 64
#define NKT (DIN / BK)    // 16

typedef __attribute__((ext_vector_type(8))) short  short8v;
typedef __attribute__((ext_vector_type(4))) short  short4v;
typedef __attribute__((ext_vector_type(4))) float  float4v;

// fp32 -> bf16 round-to-nearest-even (inputs are finite Gaussians; no NaN path)
static __device__ __forceinline__ short f2bf(float f) {
    unsigned u = __builtin_bit_cast(unsigned, f);
    u += 0x7fffu + ((u >> 16) & 1u);
    return (short)(u >> 16);
}

// LDS-only barrier (HW-verified rounds 3/6): drains ds ops but NOT vmcnt, so
// staged global loads stay in flight across it. Both barriers guard LDS
// hazards only (global loads land in private VGPRs; compiler inserts exact
// vmcnt waits at the converts).
static __device__ __forceinline__ void lds_barrier() {
    asm volatile("s_waitcnt lgkmcnt(0)\n\ts_barrier" ::: "memory");
}

__global__ __launch_bounds__(512, 2)
void pop_linear_kernel(const float* __restrict__ x,
                       const float* __restrict__ w,
                       const float* __restrict__ bias,
                       float* __restrict__ out) {
    // bf16 tiles [256 rows][64 k], row stride 128 B, single-buffered: 64 KB total.
    // In-row bytes XOR-swizzled: phys = logical ^ ((row&7)<<4), both sides (T2).
    __shared__ short As[BM * BK];   // 32 KB
    __shared__ short Bs[BN * BK];   // 32 KB

    // grid 512 = 128 pops x 4 n_tiles; bid%8 == p%8 -> x-panel sharers on one XCD
    const int bid    = blockIdx.x;
    const int k      = bid >> 3;
    const int n_tile = k & 3;
    const int p      = ((k >> 2) << 3) | (bid & 7);

    const int tid    = threadIdx.x;        // 0..511
    const int lane   = tid & 63;
    const int wave   = tid >> 6;           // 0..7 = 2(m) x 4(n)
    const int wm     = wave >> 2;          // 0..1  (row half: 128 rows)
    const int wn     = wave & 3;           // 0..3  (col quarter: 64 cols)
    const int lane15 = lane & 15;
    const int quad   = lane >> 4;          // 0..3

    const int n_base = n_tile * BN;

    // staging: thread -> row srow + 32*ps (8 passes), 256 B per row by 16 lanes
    const int srow  = tid >> 4;            // 0..31
    const int scolf = (tid & 15) * 4;      // 0..60 (floats)

    const float* Ag = x + (size_t)srow * (POP * DIN) + (size_t)p * DIN + scolf;
    const float* Bg = w + (size_t)p * ((size_t)DOUT * DIN) + (size_t)(n_base + srow) * DIN + scolf;

    const int swz = (scolf * 2) ^ ((srow & 7) << 4);

    float4v acc[8][4];
    #pragma unroll
    for (int i = 0; i < 8; ++i)
        #pragma unroll
        for (int j = 0; j < 4; ++j)
            acc[i][j] = (float4v){0.f, 0.f, 0.f, 0.f};

    float4v avr[8], bvr[8];

    const int frx = (lane15 & 7) << 4;
    const char* Ac = (const char*)As;
    const char* Bc = (const char*)Bs;

    // ---- prologue: issue stage 0 ----
    // x: normal cached loads (re-used by 3 sibling blocks + L3).
    // w: NON-TEMPORAL -- 537 MB streamed once, block-exclusive; nt marks the
    //    lines evict-first so the dead w stream stops flushing x out of L2/L3.
    #pragma unroll
    for (int ps = 0; ps < 8; ++ps) {
        avr[ps] = *(const float4v*)(Ag + (size_t)(ps * 32) * (POP * DIN));
        bvr[ps] = __builtin_nontemporal_load((const float4v*)(Bg + (size_t)(ps * 32) * DIN));
    }

    #pragma unroll 1
    for (int kt = 0; kt < NKT; ++kt) {
        lds_barrier();   // all waves' LDS reads of previous tile done

        // convert + publish (compiler inserts exact vmcnt waits for avr/bvr)
        #pragma unroll
        for (int ps = 0; ps < 8; ++ps) {
            short4v a4, b4;
            #pragma unroll
            for (int e = 0; e < 4; ++e) {
                a4[e] = f2bf(avr[ps][e]);
                b4[e] = f2bf(bvr[ps][e]);
            }
            *(short4v*)((char*)As + (ps * 32 + srow) * 128 + swz) = a4;
            *(short4v*)((char*)Bs + (ps * 32 + srow) * 128 + swz) = b4;
        }

        lds_barrier();   // writes visible

        // issue next stage -- flies across the whole compute phase
        if (kt + 1 < NKT) {
            const size_t k0 = (size_t)(kt + 1) * BK;
            #pragma unroll
            for (int ps = 0; ps < 8; ++ps) {
                avr[ps] = *(const float4v*)(Ag + (size_t)(ps * 32) * (POP * DIN) + k0);
                bvr[ps] = __builtin_nontemporal_load((const float4v*)(Bg + (size_t)(ps * 32) * DIN + k0));
            }
        }

        // compute: 2 k-chunks of 32; per wave 8x4 fragments, 64 MFMA per step
        #pragma unroll
        for (int kk = 0; kk < 2; ++kk) {
            const int cb = (kk * 64 + quad * 16) ^ frx;
            short8v bfr[4];
            #pragma unroll
            for (int j = 0; j < 4; ++j)
                bfr[j] = *(const short8v*)(Bc + (wn * 64 + j * 16 + lane15) * 128 + cb);
            #pragma unroll
            for (int i = 0; i < 8; ++i) {
                short8v afr = *(const short8v*)(Ac + (wm * 128 + i * 16 + lane15) * 128 + cb);
                #pragma unroll
                for (int j = 0; j < 4; ++j)
                    acc[i][j] = __builtin_amdgcn_mfma_f32_16x16x32_bf16(afr, bfr[j], acc[i][j], 0, 0, 0);
            }
        }
    }

    // epilogue: C/D layout m = quad*4 + reg, n = lane&15 (HW-verified mapping)
    const float* bp = bias + (size_t)p * DOUT;
    float bj[4];
    #pragma unroll
    for (int j = 0; j < 4; ++j)
        bj[j] = bp[n_base + wn * 64 + j * 16 + lane15];

    #pragma unroll
    for (int i = 0; i < 8; ++i) {
        #pragma unroll
        for (int r = 0; r < 4; ++r) {
            const int m = wm * 128 + i * 16 + quad * 4 + r;
            float* orow = out + (size_t)m * (POP * DOUT) + (size_t)p * DOUT;
            #pragma unroll
            for (int j = 0; j < 4; ++j) {
                const int n = n_base + wn * 64 + j * 16 + lane15;
                orow[n] = acc[i][j][r] + bj[j];
            }
        }
    }
}

extern "C" void kernel_launch(void* const* d_in, const int* in_sizes, int n_in,
                              void* d_out, int out_size, void* d_ws, size_t ws_size,
                              hipStream_t stream) {
    const float* x    = (const float*)d_in[0];
    const float* w    = (const float*)d_in[1];
    const float* bias = (const float*)d_in[2];
    float* out        = (float*)d_out;

    const int grid = POP * (DOUT / BN);  // 128 * 4 = 512
    pop_linear_kernel<<<grid, 512, 0, stream>>>(x, w, bias, out);
}

// Round 11
// 818.827 us; speedup vs baseline: 2.0563x; 1.0037x over previous
//
#include <hip/hip_runtime.h>

#define POP   128
#define BATCH 256
#define DIN   1024
#define DOUT  1024

#define BM 256            // full batch: w panel loaded once (compulsory)
#define BN 256            // x panel loaded 4x (issued), L2-shared on one XCD
#define BK 64
#define NKT (DIN / BK)    // 16

typedef __attribute__((ext_vector_type(8))) short  short8v;
typedef __attribute__((ext_vector_type(4))) short  short4v;
typedef __attribute__((ext_vector_type(4))) float  float4v;

// fp32 -> bf16 round-to-nearest-even (inputs are finite Gaussians; no NaN path)
static __device__ __forceinline__ short f2bf(float f) {
    unsigned u = __builtin_bit_cast(unsigned, f);
    u += 0x7fffu + ((u >> 16) & 1u);
    return (short)(u >> 16);
}

// LDS-only barrier (HW-verified rounds 3/6): drains ds ops but NOT vmcnt, so
// staged global loads stay in flight across it. Both barriers guard LDS
// hazards only (global loads land in private VGPRs; compiler inserts exact
// vmcnt waits at the converts).
static __device__ __forceinline__ void lds_barrier() {
    asm volatile("s_waitcnt lgkmcnt(0)\n\ts_barrier" ::: "memory");
}

__global__ __launch_bounds__(512, 2)
void pop_linear_kernel(const float* __restrict__ x,
                       const float* __restrict__ w,
                       const float* __restrict__ bias,
                       float* __restrict__ out) {
    // bf16 tiles [256 rows][64 k], row stride 128 B, single-buffered: 64 KB total.
    // In-row bytes XOR-swizzled: phys = logical ^ ((row&7)<<4), both sides (T2).
    __shared__ short As[BM * BK];   // 32 KB
    __shared__ short Bs[BN * BK];   // 32 KB

    // grid 512 = 128 pops x 4 n_tiles; bid%8 == p%8 -> x-panel sharers on one XCD
    const int bid    = blockIdx.x;
    const int k      = bid >> 3;
    const int n_tile = k & 3;
    const int p      = ((k >> 2) << 3) | (bid & 7);

    const int tid    = threadIdx.x;        // 0..511
    const int lane   = tid & 63;
    const int wave   = tid >> 6;           // 0..7 = 2(m) x 4(n)
    const int wm     = wave >> 2;          // 0..1  (row half: 128 rows)
    const int wn     = wave & 3;           // 0..3  (col quarter: 64 cols)
    const int lane15 = lane & 15;
    const int quad   = lane >> 4;          // 0..3

    const int n_base = n_tile * BN;

    // staging: thread -> row srow + 32*ps (8 passes), 256 B per row by 16 lanes
    const int srow  = tid >> 4;            // 0..31
    const int scolf = (tid & 15) * 4;      // 0..60 (floats)

    const float* Ag = x + (size_t)srow * (POP * DIN) + (size_t)p * DIN + scolf;
    const float* Bg = w + (size_t)p * ((size_t)DOUT * DIN) + (size_t)(n_base + srow) * DIN + scolf;

    const int swz = (scolf * 2) ^ ((srow & 7) << 4);

    float4v acc[8][4];
    #pragma unroll
    for (int i = 0; i < 8; ++i)
        #pragma unroll
        for (int j = 0; j < 4; ++j)
            acc[i][j] = (float4v){0.f, 0.f, 0.f, 0.f};

    float4v avr[8], bvr[8];

    const int frx = (lane15 & 7) << 4;
    const char* Ac = (const char*)As;
    const char* Bc = (const char*)Bs;

    // ---- prologue: issue stage 0 ----
    // x: normal cached loads (re-used by 3 sibling blocks + L3).
    // w: NON-TEMPORAL -- 537 MB streamed once, block-exclusive; nt marks the
    //    lines evict-first so the dead w stream stops flushing x out of L2/L3.
    #pragma unroll
    for (int ps = 0; ps < 8; ++ps) {
        avr[ps] = *(const float4v*)(Ag + (size_t)(ps * 32) * (POP * DIN));
        bvr[ps] = __builtin_nontemporal_load((const float4v*)(Bg + (size_t)(ps * 32) * DIN));
    }

    #pragma unroll 1
    for (int kt = 0; kt < NKT; ++kt) {
        lds_barrier();   // all waves' LDS reads of previous tile done

        // convert + publish (compiler inserts exact vmcnt waits for avr/bvr)
        #pragma unroll
        for (int ps = 0; ps < 8; ++ps) {
            short4v a4, b4;
            #pragma unroll
            for (int e = 0; e < 4; ++e) {
                a4[e] = f2bf(avr[ps][e]);
                b4[e] = f2bf(bvr[ps][e]);
            }
            *(short4v*)((char*)As + (ps * 32 + srow) * 128 + swz) = a4;
            *(short4v*)((char*)Bs + (ps * 32 + srow) * 128 + swz) = b4;
        }

        lds_barrier();   // writes visible

        // issue next stage -- flies across the whole compute phase
        if (kt + 1 < NKT) {
            const size_t k0 = (size_t)(kt + 1) * BK;
            #pragma unroll
            for (int ps = 0; ps < 8; ++ps) {
                avr[ps] = *(const float4v*)(Ag + (size_t)(ps * 32) * (POP * DIN) + k0);
                bvr[ps] = __builtin_nontemporal_load((const float4v*)(Bg + (size_t)(ps * 32) * DIN + k0));
            }
        }

        // compute: 2 k-chunks of 32; per wave 8x4 fragments, 64 MFMA per step
        #pragma unroll
        for (int kk = 0; kk < 2; ++kk) {
            const int cb = (kk * 64 + quad * 16) ^ frx;
            short8v bfr[4];
            #pragma unroll
            for (int j = 0; j < 4; ++j)
                bfr[j] = *(const short8v*)(Bc + (wn * 64 + j * 16 + lane15) * 128 + cb);
            #pragma unroll
            for (int i = 0; i < 8; ++i) {
                short8v afr = *(const short8v*)(Ac + (wm * 128 + i * 16 + lane15) * 128 + cb);
                #pragma unroll
                for (int j = 0; j < 4; ++j)
                    acc[i][j] = __builtin_amdgcn_mfma_f32_16x16x32_bf16(afr, bfr[j], acc[i][j], 0, 0, 0);
            }
        }
    }

    // epilogue: C/D layout m = quad*4 + reg, n = lane&15 (HW-verified mapping).
    // NON-TEMPORAL stores: out is 134 MB written once, never re-read -- keep its
    // lines evict-first so the write burst doesn't flush x/w from L2/L3.
    const float* bp = bias + (size_t)p * DOUT;
    float bj[4];
    #pragma unroll
    for (int j = 0; j < 4; ++j)
        bj[j] = bp[n_base + wn * 64 + j * 16 + lane15];

    #pragma unroll
    for (int i = 0; i < 8; ++i) {
        #pragma unroll
        for (int r = 0; r < 4; ++r) {
            const int m = wm * 128 + i * 16 + quad * 4 + r;
            float* orow = out + (size_t)m * (POP * DOUT) + (size_t)p * DOUT;
            #pragma unroll
            for (int j = 0; j < 4; ++j) {
                const int n = n_base + wn * 64 + j * 16 + lane15;
                __builtin_nontemporal_store(acc[i][j][r] + bj[j], &orow[n]);
            }
        }
    }
}

extern "C" void kernel_launch(void* const* d_in, const int* in_sizes, int n_in,
                              void* d_out, int out_size, void* d_ws, size_t ws_size,
                              hipStream_t stream) {
    const float* x    = (const float*)d_in[0];
    const float* w    = (const float*)d_in[1];
    const float* bias = (const float*)d_in[2];
    float* out        = (float*)d_out;

    const int grid = POP * (DOUT / BN);  // 128 * 4 = 512
    pop_linear_kernel<<<grid, 512, 0, stream>>>(x, w, bias, out);
}